// Round 22
// baseline (201.497 us; speedup 1.0000x reference)
//
#include <hip/hip_runtime.h>
#include <hip/hip_bf16.h>
#include <stdint.h>

#define NN 50000
#define NE 1600000
#define CAPN 96          // csr slots per node (deg ~ Poisson(32), +11 sigma)
#define NYB 391          // y blocks: 128 rows each
#define WST 260          // WlT row stride: 256 + 4 pad
#define NDB 49           // dinv blocks (49*1024 >= NN)

// ---------------- launch 1: collapsed weights ----------------
__global__ __launch_bounds__(1024) void k_w(const float* __restrict__ W1, const float* __restrict__ b1,
                                            const float* __restrict__ W2, const float* __restrict__ b2,
                                            const float* __restrict__ Wc, const float* __restrict__ bc,
                                            float* __restrict__ Wcombo, float* __restrict__ c12){
  const int t = threadIdx.x;
  __shared__ float M1[1024];
  { // M1 = W2@Wc [128,8], one element per thread
    int k = t >> 3, c = t & 7;
    float s = 0.f;
    for (int j = 0; j < 64; ++j) s += W2[k * 64 + j] * Wc[j * 8 + c];
    M1[t] = s;
  }
  __syncthreads();
  for (int idx = t; idx < 2048; idx += 1024){
    int i = idx >> 3, c = idx & 7;
    float s = 0.f;
    for (int k = 0; k < 128; ++k) s += W1[i * 128 + k] * M1[k * 8 + c];
    Wcombo[idx] = s;
  }
  if (t < 8){
    float s = 0.f;
    for (int k = 0; k < 128; ++k) s += b1[k] * M1[k * 8 + t];
    c12[t] = s;
  } else if (t < 16){
    int c = t - 8;
    float s = bc[c];
    for (int k = 0; k < 64; ++k) s += b2[k] * Wc[k * 8 + c];
    c12[t] = s;
  }
}

// ---------------- launch 2: direct scatter into per-node regions ----------------
__global__ __launch_bounds__(1024) void k_scat2(const int* __restrict__ src, const int* __restrict__ dst,
                                                int* __restrict__ cnt, unsigned short* __restrict__ csr){
  int i = blockIdx.x * 1024 + threadIdx.x;      // pair index
  if (i * 2 >= NE) return;
  int2 d = ((const int2*)dst)[i];
  int2 s = ((const int2*)src)[i];
  int p0 = atomicAdd(&cnt[d.x], 1);
  csr[(size_t)d.x * CAPN + p0] = (unsigned short)s.x;
  int p1 = atomicAdd(&cnt[d.y], 1);
  csr[(size_t)d.y * CAPN + p1] = (unsigned short)s.y;
}

// ---------------- launch 3: [dinv: blocks 0..48 | Yraw: blocks 49..439] ----------------
__global__ __launch_bounds__(1024) void k_dy(const int* __restrict__ cnt, float* __restrict__ dinv,
                                             const float* __restrict__ X, const float* __restrict__ Wcombo,
                                             float* __restrict__ Yraw){
  const int t = threadIdx.x;
  if (blockIdx.x < NDB){
    int node = blockIdx.x * 1024 + t;
    if (node < NN) dinv[node] = rsqrtf((float)(cnt[node] + 1));
  } else {
    __shared__ float WlT[8 * WST];     // [c][k] stride 260: banks (4c+k)%32, rows 16B-aligned
    for (int i = t; i < 2048; i += 1024)
      WlT[(i & 7) * WST + (i >> 3)] = Wcombo[i];
    __syncthreads();
    int gid = (blockIdx.x - NDB) * 1024 + t;
    int row = gid >> 3, c = gid & 7;
    if (row >= NN) return;
    const float* Xr = X + (size_t)row * 256;
    const float* Wp = &WlT[c * WST];
    float a0 = 0.f, a1 = 0.f;
    #pragma unroll 8
    for (int k = 0; k < 256; k += 8){
      float4 w0 = *(const float4*)(Wp + k);
      float4 w1 = *(const float4*)(Wp + k + 4);
      float4 x0 = *(const float4*)(Xr + k);
      float4 x1 = *(const float4*)(Xr + k + 4);
      a0 += x0.x * w0.x + x0.y * w0.y + x0.z * w0.z + x0.w * w0.w;
      a1 += x1.x * w1.x + x1.y * w1.y + x1.z * w1.z + x1.w * w1.w;
    }
    Yraw[(size_t)row * 8 + c] = a0 + a1;
  }
}

// ---------------- launch 4: agg pass 1, 8 lanes/node ----------------
// U = di^2*(sum_s dinv_s*Yraw_s + di*Yraw_d);  V = di*(sum_s dinv_s + di)
__global__ __launch_bounds__(256) void k_agg1(const unsigned short* __restrict__ csr, const int* __restrict__ cnt,
                                              const float* __restrict__ dinv, const float* __restrict__ Y,
                                              float* __restrict__ U, float* __restrict__ V){
  int gid = blockIdx.x * 256 + threadIdx.x;
  int node = gid >> 3, c = gid & 7;
  if (node >= NN) return;
  int e = node * CAPN;
  const int e1 = e + cnt[node];
  float a = 0.f, vd = 0.f;
  for (; e + 4 <= e1; e += 4){
    int s0 = csr[e], s1 = csr[e + 1], s2 = csr[e + 2], s3 = csr[e + 3];
    float d0 = dinv[s0], d1 = dinv[s1], d2 = dinv[s2], d3 = dinv[s3];
    float y0 = Y[(size_t)s0 * 8 + c], y1 = Y[(size_t)s1 * 8 + c];
    float y2 = Y[(size_t)s2 * 8 + c], y3 = Y[(size_t)s3 * 8 + c];
    a += (d0 * y0 + d1 * y1) + (d2 * y2 + d3 * y3);
    vd += (d0 + d1) + (d2 + d3);
  }
  for (; e < e1; ++e){
    int s0 = csr[e];
    float d0 = dinv[s0];
    a += d0 * Y[(size_t)s0 * 8 + c];
    vd += d0;
  }
  float di = dinv[node];
  U[(size_t)node * 8 + c] = di * di * (a + di * Y[(size_t)node * 8 + c]);
  if (c == 0) V[node] = di * (vd + di);
}

// ---------------- launch 5: agg pass 2: out = di*(sum_s U_s + U_d) + V*c1 + c2 ----------------
__global__ __launch_bounds__(256) void k_agg2(const unsigned short* __restrict__ csr, const int* __restrict__ cnt,
                                              const float* __restrict__ dinv, const float* __restrict__ U,
                                              const float* __restrict__ V, const float* __restrict__ c12,
                                              float* __restrict__ O){
  int gid = blockIdx.x * 256 + threadIdx.x;
  int node = gid >> 3, c = gid & 7;
  if (node >= NN) return;
  int e = node * CAPN;
  const int e1 = e + cnt[node];
  float a = 0.f;
  for (; e + 4 <= e1; e += 4){
    int s0 = csr[e], s1 = csr[e + 1], s2 = csr[e + 2], s3 = csr[e + 3];
    float y0 = U[(size_t)s0 * 8 + c], y1 = U[(size_t)s1 * 8 + c];
    float y2 = U[(size_t)s2 * 8 + c], y3 = U[(size_t)s3 * 8 + c];
    a += (y0 + y1) + (y2 + y3);
  }
  for (; e < e1; ++e){
    int s0 = csr[e];
    a += U[(size_t)s0 * 8 + c];
  }
  float di = dinv[node];
  O[(size_t)node * 8 + c] = di * (a + U[(size_t)node * 8 + c]) + V[node] * c12[c] + c12[8 + c];
}

extern "C" void kernel_launch(void* const* d_in, const int* in_sizes, int n_in,
                              void* d_out, int out_size, void* d_ws, size_t ws_size,
                              hipStream_t stream) {
  const float* seq = (const float*)d_in[0];
  const int*   ei  = (const int*)d_in[1];
  const int*   esrc = ei;
  const int*   edst = ei + NE;
  const float* W1 = (const float*)d_in[2];
  const float* b1 = (const float*)d_in[3];
  const float* W2 = (const float*)d_in[4];
  const float* b2 = (const float*)d_in[5];
  const float* Wc = (const float*)d_in[6];
  const float* bc = (const float*)d_in[7];
  float* out = (float*)d_out;

  char* ws = (char*)d_ws;
  size_t o = 0;
  auto alloc = [&](size_t bytes) -> void* {
    void* p = ws + o;
    o += (bytes + 255) & ~(size_t)255;
    return p;
  };
  int*      cnt  = (int*)alloc((size_t)NN * 4);
  unsigned short* csr = (unsigned short*)alloc((size_t)NN * CAPN * 2);  // 9.6 MB
  float*    dinv = (float*)alloc((size_t)NN * 4);
  float*    Wcb  = (float*)alloc(2048 * 4);
  float*    c12  = (float*)alloc(16 * 4);
  float*    Yraw = (float*)alloc((size_t)NN * 8 * 4);
  float*    U    = (float*)alloc((size_t)NN * 8 * 4);
  float*    V    = (float*)alloc((size_t)NN * 4);

  hipMemsetAsync(cnt, 0, (size_t)NN * 4, stream);
  k_w     <<<1, 1024, 0, stream>>>(W1, b1, W2, b2, Wc, bc, Wcb, c12);
  k_scat2 <<<(NE / 2 + 1023) / 1024, 1024, 0, stream>>>(esrc, edst, cnt, csr);
  k_dy    <<<NDB + NYB, 1024, 0, stream>>>(cnt, dinv, seq, Wcb, Yraw);
  k_agg1  <<<1563, 256, 0, stream>>>(csr, cnt, dinv, Yraw, U, V);
  k_agg2  <<<1563, 256, 0, stream>>>(csr, cnt, dinv, U, V, c12, out);
}